// Round 3
// baseline (337.705 us; speedup 1.0000x reference)
//
#include <hip/hip_runtime.h>

#define EPS 1e-10f

typedef float v4f __attribute__((ext_vector_type(4)));

// Batch-invariant parameters, loaded once per thread (uniform -> s_loads).
struct Params {
    float omega, r, half_lam;
    float mu20r, mu21r, dmu0, dmu1;        // mu2-r, mu1-mu2
    float s2a, s2b, s2c, da, db, dc;       // Sigma2 tri, Sigma1-Sigma2 tri
    float phi00, phi01, phi10, phi11;
    float sp00, sp01, sp11;                // spd_core (symmetric)
};

// One batch element: 2 v_rsq + ~25 FMA, no div/sqrt.
__device__ __forceinline__ void compute_one(
    float xe, float pe, float de, float fe, const Params& P,
    float& m0, float& m1, v4f& cv)
{
    float om = 1.0f - pe;

    // Sigma_bar = Sigma2 + p*(Sigma1-Sigma2) + EPS*I
    float a  = fmaf(pe, P.da, P.s2a) + EPS;
    float b  = fmaf(pe, P.db, P.s2b);
    float cc = fmaf(pe, P.dc, P.s2c) + EPS;

    // Cholesky via rsqrt: L=[[l00,0],[t,l11]], U=L^T
    float inv_l00 = __builtin_amdgcn_rsqf(a);
    float t       = b * inv_l00;                 // l10
    float dd      = fmaf(-t, t, cc);             // Schur complement = l11^2
    float inv_l11 = __builtin_amdgcn_rsqf(dd);

    // mu_bar - r
    float mb0 = fmaf(pe, P.dmu0, P.mu20r);
    float mb1 = fmaf(pe, P.dmu1, P.mu21r);

    // adj = p*(1 - dlnf_dp*(1-p)); signal_i = mb_i * (phi_i0*adj + phi_i1)
    float adj  = pe * fmaf(-de, om, 1.0f);
    float sig0 = mb0 * fmaf(P.phi00, adj, P.phi01);
    float sig1 = mb1 * fmaf(P.phi10, adj, P.phi11);

    // back-substitution: U x = sig
    float sti1 = sig1 * inv_l11;
    float sti0 = fmaf(-t, sti1, sig0) * inv_l00;

    float nxo = P.omega - xe;
    m0 = nxo * sti0;
    m1 = nxo * sti1;

    // inv_U = [[1/l00, -t/(l00*l11)],[0, 1/l11]]
    float iu00 = inv_l00;
    float iu11 = inv_l11;
    float iu01 = -(t * inv_l00) * inv_l11;

    // C = inv_U @ spd @ inv_U^T
    float M00 = fmaf(iu00, P.sp00, iu01 * P.sp01);
    float M01 = fmaf(iu00, P.sp01, iu01 * P.sp11);
    float M10 = iu11 * P.sp01;
    float M11 = iu11 * P.sp11;
    float C00 = fmaf(M00, iu00, M01 * iu01);
    float C01 = M01 * iu11;
    float C10 = fmaf(M10, iu00, M11 * iu01);
    float C11 = M11 * iu11;

    float scale = P.half_lam * fe;               // 0.5*lambda*f
    float off   = 0.5f * scale * (C01 + C10);
    cv.x = fmaf(scale, C00, EPS);
    cv.y = off;
    cv.z = off;
    cv.w = fmaf(scale, C11, EPS);
}

__device__ __forceinline__ Params load_params(
    const float* omega_p, const float* mu1, const float* mu2,
    const float* S1, const float* S2, const float* phi, const float* ct,
    const int* lambda_p, const int* r_p)
{
    Params P;
    P.omega    = omega_p[0];
    float lam  = (float)lambda_p[0];
    P.half_lam = 0.5f * lam;
    P.r        = (float)r_p[0];
    float mu10 = mu1[0], mu11 = mu1[1], mu20 = mu2[0], mu21 = mu2[1];
    P.mu20r = mu20 - P.r;  P.mu21r = mu21 - P.r;
    P.dmu0  = mu10 - mu20; P.dmu1  = mu11 - mu21;
    P.s2a = S2[0]; P.s2b = S2[2]; P.s2c = S2[3];
    P.da  = S1[0] - P.s2a; P.db = S1[2] - P.s2b; P.dc = S1[3] - P.s2c;
    P.phi00 = phi[0]; P.phi01 = phi[1]; P.phi10 = phi[2]; P.phi11 = phi[3];
    // spd_core from cov_tril_unconstrained: tril=[[e^ct00,0],[ct10,e^ct11]]
    float e0 = expf(ct[0]);
    float e1 = expf(ct[3]);
    float t10 = ct[2];
    P.sp00 = e0 * e0;
    P.sp01 = t10 * e0;
    P.sp11 = fmaf(t10, t10, e1 * e1);
    return P;
}

// 8 elements per thread: 8 float4 loads in flight per lane (128 B) so HBM
// latency is covered by Little's law (~9 KB/CU needed; ~30 waves/CU * 8 KB/wave).
__global__ __launch_bounds__(256) void poemv_kernel(
    const float* __restrict__ x, const float* __restrict__ omega_p,
    const float* __restrict__ p, const float* __restrict__ dlnf_dp,
    const float* __restrict__ f,
    const float* __restrict__ mu1, const float* __restrict__ mu2,
    const float* __restrict__ S1, const float* __restrict__ S2,
    const float* __restrict__ phi, const float* __restrict__ ct,
    const int* __restrict__ lambda_p, const int* __restrict__ r_p,
    float* __restrict__ out_mean, float* __restrict__ out_cov, int B)
{
    int tid = blockIdx.x * blockDim.x + threadIdx.x;
    long b0 = (long)tid * 8;
    if (b0 >= B) return;

    Params P = load_params(omega_p, mu1, mu2, S1, S2, phi, ct, lambda_p, r_p);

    if (b0 + 7 < B) {
        // issue all 8 loads up front (native vectors)
        const v4f* x4 = (const v4f*)x;
        const v4f* p4 = (const v4f*)p;
        const v4f* d4 = (const v4f*)dlnf_dp;
        const v4f* f4 = (const v4f*)f;
        int q = tid * 2;
        v4f xa = x4[q],     xb = x4[q + 1];
        v4f pa = p4[q],     pb = p4[q + 1];
        v4f da = d4[q],     db = d4[q + 1];
        v4f fa = f4[q],     fb = f4[q + 1];

        float xs[8] = {xa.x, xa.y, xa.z, xa.w, xb.x, xb.y, xb.z, xb.w};
        float ps[8] = {pa.x, pa.y, pa.z, pa.w, pb.x, pb.y, pb.z, pb.w};
        float ds[8] = {da.x, da.y, da.z, da.w, db.x, db.y, db.z, db.w};
        float fs[8] = {fa.x, fa.y, fa.z, fa.w, fb.x, fb.y, fb.z, fb.w};

        v4f* mo = (v4f*)(out_mean + b0 * 2);   // 16 floats = 4x v4f
        v4f* co = (v4f*)(out_cov  + b0 * 4);   // 32 floats = 8x v4f

        #pragma unroll
        for (int k = 0; k < 4; ++k) {
            float m0, m1, m2, m3;
            v4f c0, c1;
            compute_one(xs[2*k],   ps[2*k],   ds[2*k],   fs[2*k],   P, m0, m1, c0);
            compute_one(xs[2*k+1], ps[2*k+1], ds[2*k+1], fs[2*k+1], P, m2, m3, c1);
            v4f mv = {m0, m1, m2, m3};
            __builtin_nontemporal_store(mv, mo + k);
            __builtin_nontemporal_store(c0, co + 2*k);
            __builtin_nontemporal_store(c1, co + 2*k + 1);
        }
    } else {
        for (long b = b0; b < B; ++b) {
            float m0, m1; v4f cv;
            compute_one(x[b], p[b], dlnf_dp[b], f[b], P, m0, m1, cv);
            out_mean[b * 2 + 0] = m0;
            out_mean[b * 2 + 1] = m1;
            ((v4f*)out_cov)[b] = cv;
        }
    }
}

extern "C" void kernel_launch(void* const* d_in, const int* in_sizes, int n_in,
                              void* d_out, int out_size, void* d_ws, size_t ws_size,
                              hipStream_t stream) {
    const float* x     = (const float*)d_in[0];
    const float* omega = (const float*)d_in[1];
    const float* p     = (const float*)d_in[2];
    const float* dlnf  = (const float*)d_in[3];
    const float* f     = (const float*)d_in[4];
    const float* mu1   = (const float*)d_in[5];
    const float* mu2   = (const float*)d_in[6];
    const float* S1    = (const float*)d_in[7];
    const float* S2    = (const float*)d_in[8];
    const float* phi   = (const float*)d_in[9];
    const float* ct    = (const float*)d_in[10];
    const int*   lam   = (const int*)d_in[11];
    const int*   r     = (const int*)d_in[12];

    int B = in_sizes[0];
    float* out_mean = (float*)d_out;
    float* out_cov  = out_mean + (size_t)B * 2;

    int threads = 256;
    long n_thr = ((long)B + 7) / 8;
    int blocks = (int)((n_thr + threads - 1) / threads);
    poemv_kernel<<<blocks, threads, 0, stream>>>(
        x, omega, p, dlnf, f, mu1, mu2, S1, S2, phi, ct, lam, r,
        out_mean, out_cov, B);
}

// Round 4
// 191.977 us; speedup vs baseline: 1.7591x; 1.7591x over previous
//
#include <hip/hip_runtime.h>

#define EPS 1e-10f

typedef float v4f __attribute__((ext_vector_type(4)));

// Batch-invariant parameters, loaded once per thread (uniform -> s_loads).
struct Params {
    float omega, r, half_lam;
    float mu20r, mu21r, dmu0, dmu1;        // mu2-r, mu1-mu2
    float s2a, s2b, s2c, da, db, dc;       // Sigma2 tri, Sigma1-Sigma2 tri
    float phi00, phi01, phi10, phi11;
    float sp00, sp01, sp11;                // spd_core (symmetric)
};

// One batch element: 2 v_rsq + ~25 FMA, no div/sqrt.
__device__ __forceinline__ void compute_one(
    float xe, float pe, float de, float fe, const Params& P,
    float& m0, float& m1, v4f& cv)
{
    float om = 1.0f - pe;

    // Sigma_bar = Sigma2 + p*(Sigma1-Sigma2) + EPS*I
    float a  = fmaf(pe, P.da, P.s2a) + EPS;
    float b  = fmaf(pe, P.db, P.s2b);
    float cc = fmaf(pe, P.dc, P.s2c) + EPS;

    // Cholesky via rsqrt: L=[[l00,0],[t,l11]], U=L^T
    float inv_l00 = __builtin_amdgcn_rsqf(a);
    float t       = b * inv_l00;                 // l10
    float dd      = fmaf(-t, t, cc);             // Schur complement = l11^2
    float inv_l11 = __builtin_amdgcn_rsqf(dd);

    // mu_bar - r
    float mb0 = fmaf(pe, P.dmu0, P.mu20r);
    float mb1 = fmaf(pe, P.dmu1, P.mu21r);

    // adj = p*(1 - dlnf_dp*(1-p)); signal_i = mb_i * (phi_i0*adj + phi_i1)
    float adj  = pe * fmaf(-de, om, 1.0f);
    float sig0 = mb0 * fmaf(P.phi00, adj, P.phi01);
    float sig1 = mb1 * fmaf(P.phi10, adj, P.phi11);

    // back-substitution: U x = sig
    float sti1 = sig1 * inv_l11;
    float sti0 = fmaf(-t, sti1, sig0) * inv_l00;

    float nxo = P.omega - xe;
    m0 = nxo * sti0;
    m1 = nxo * sti1;

    // inv_U = [[1/l00, -t/(l00*l11)],[0, 1/l11]]
    float iu00 = inv_l00;
    float iu11 = inv_l11;
    float iu01 = -(t * inv_l00) * inv_l11;

    // C = inv_U @ spd @ inv_U^T
    float M00 = fmaf(iu00, P.sp00, iu01 * P.sp01);
    float M01 = fmaf(iu00, P.sp01, iu01 * P.sp11);
    float M10 = iu11 * P.sp01;
    float M11 = iu11 * P.sp11;
    float C00 = fmaf(M00, iu00, M01 * iu01);
    float C01 = M01 * iu11;
    float C10 = fmaf(M10, iu00, M11 * iu01);
    float C11 = M11 * iu11;

    float scale = P.half_lam * fe;               // 0.5*lambda*f
    float off   = 0.5f * scale * (C01 + C10);
    cv.x = fmaf(scale, C00, EPS);
    cv.y = off;
    cv.z = off;
    cv.w = fmaf(scale, C11, EPS);
}

__device__ __forceinline__ Params load_params(
    const float* omega_p, const float* mu1, const float* mu2,
    const float* S1, const float* S2, const float* phi, const float* ct,
    const int* lambda_p, const int* r_p)
{
    Params P;
    P.omega    = omega_p[0];
    float lam  = (float)lambda_p[0];
    P.half_lam = 0.5f * lam;
    P.r        = (float)r_p[0];
    float mu10 = mu1[0], mu11 = mu1[1], mu20 = mu2[0], mu21 = mu2[1];
    P.mu20r = mu20 - P.r;  P.mu21r = mu21 - P.r;
    P.dmu0  = mu10 - mu20; P.dmu1  = mu11 - mu21;
    P.s2a = S2[0]; P.s2b = S2[2]; P.s2c = S2[3];
    P.da  = S1[0] - P.s2a; P.db = S1[2] - P.s2b; P.dc = S1[3] - P.s2c;
    P.phi00 = phi[0]; P.phi01 = phi[1]; P.phi10 = phi[2]; P.phi11 = phi[3];
    // spd_core from cov_tril_unconstrained: tril=[[e^ct00,0],[ct10,e^ct11]]
    float e0 = expf(ct[0]);
    float e1 = expf(ct[3]);
    float t10 = ct[2];
    P.sp00 = e0 * e0;
    P.sp01 = t10 * e0;
    P.sp11 = fmaf(t10, t10, e1 * e1);
    return P;
}

// 8 elements per thread: 8 float4 loads in flight per lane (128 B).
// Plain L2-write-combined stores: nontemporal stores caused 2.5x HBM write
// amplification (WRITE_SIZE 101->249 MB) on gfx950 — do NOT use nt here.
__global__ __launch_bounds__(256) void poemv_kernel(
    const float* __restrict__ x, const float* __restrict__ omega_p,
    const float* __restrict__ p, const float* __restrict__ dlnf_dp,
    const float* __restrict__ f,
    const float* __restrict__ mu1, const float* __restrict__ mu2,
    const float* __restrict__ S1, const float* __restrict__ S2,
    const float* __restrict__ phi, const float* __restrict__ ct,
    const int* __restrict__ lambda_p, const int* __restrict__ r_p,
    float* __restrict__ out_mean, float* __restrict__ out_cov, int B)
{
    int tid = blockIdx.x * blockDim.x + threadIdx.x;
    long b0 = (long)tid * 8;
    if (b0 >= B) return;

    Params P = load_params(omega_p, mu1, mu2, S1, S2, phi, ct, lambda_p, r_p);

    if (b0 + 7 < B) {
        // issue all 8 loads up front (native vectors)
        const v4f* x4 = (const v4f*)x;
        const v4f* p4 = (const v4f*)p;
        const v4f* d4 = (const v4f*)dlnf_dp;
        const v4f* f4 = (const v4f*)f;
        int q = tid * 2;
        v4f xa = x4[q],     xb = x4[q + 1];
        v4f pa = p4[q],     pb = p4[q + 1];
        v4f da = d4[q],     db = d4[q + 1];
        v4f fa = f4[q],     fb = f4[q + 1];

        float xs[8] = {xa.x, xa.y, xa.z, xa.w, xb.x, xb.y, xb.z, xb.w};
        float ps[8] = {pa.x, pa.y, pa.z, pa.w, pb.x, pb.y, pb.z, pb.w};
        float ds[8] = {da.x, da.y, da.z, da.w, db.x, db.y, db.z, db.w};
        float fs[8] = {fa.x, fa.y, fa.z, fa.w, fb.x, fb.y, fb.z, fb.w};

        v4f* mo = (v4f*)(out_mean + b0 * 2);   // 16 floats = 4x v4f
        v4f* co = (v4f*)(out_cov  + b0 * 4);   // 32 floats = 8x v4f

        #pragma unroll
        for (int k = 0; k < 4; ++k) {
            float m0, m1, m2, m3;
            v4f c0, c1;
            compute_one(xs[2*k],   ps[2*k],   ds[2*k],   fs[2*k],   P, m0, m1, c0);
            compute_one(xs[2*k+1], ps[2*k+1], ds[2*k+1], fs[2*k+1], P, m2, m3, c1);
            v4f mv = {m0, m1, m2, m3};
            mo[k]       = mv;
            co[2*k]     = c0;
            co[2*k + 1] = c1;
        }
    } else {
        for (long b = b0; b < B; ++b) {
            float m0, m1; v4f cv;
            compute_one(x[b], p[b], dlnf_dp[b], f[b], P, m0, m1, cv);
            out_mean[b * 2 + 0] = m0;
            out_mean[b * 2 + 1] = m1;
            ((v4f*)out_cov)[b] = cv;
        }
    }
}

extern "C" void kernel_launch(void* const* d_in, const int* in_sizes, int n_in,
                              void* d_out, int out_size, void* d_ws, size_t ws_size,
                              hipStream_t stream) {
    const float* x     = (const float*)d_in[0];
    const float* omega = (const float*)d_in[1];
    const float* p     = (const float*)d_in[2];
    const float* dlnf  = (const float*)d_in[3];
    const float* f     = (const float*)d_in[4];
    const float* mu1   = (const float*)d_in[5];
    const float* mu2   = (const float*)d_in[6];
    const float* S1    = (const float*)d_in[7];
    const float* S2    = (const float*)d_in[8];
    const float* phi   = (const float*)d_in[9];
    const float* ct    = (const float*)d_in[10];
    const int*   lam   = (const int*)d_in[11];
    const int*   r     = (const int*)d_in[12];

    int B = in_sizes[0];
    float* out_mean = (float*)d_out;
    float* out_cov  = out_mean + (size_t)B * 2;

    int threads = 256;
    long n_thr = ((long)B + 7) / 8;
    int blocks = (int)((n_thr + threads - 1) / threads);
    poemv_kernel<<<blocks, threads, 0, stream>>>(
        x, omega, p, dlnf, f, mu1, mu2, S1, S2, phi, ct, lam, r,
        out_mean, out_cov, B);
}

// Round 5
// 167.372 us; speedup vs baseline: 2.0177x; 1.1470x over previous
//
#include <hip/hip_runtime.h>

#define EPS 1e-10f

typedef float v4f __attribute__((ext_vector_type(4)));
typedef float v2f __attribute__((ext_vector_type(2)));

// Batch-invariant parameters (uniform -> scalar loads).
struct Params {
    float omega, half_lam;
    float mu20r, mu21r, dmu0, dmu1;        // mu2-r, mu1-mu2
    float s2a, s2b, s2c, da, db, dc;       // Sigma2 tri, Sigma1-Sigma2 tri
    float phi00, phi01, phi10, phi11;
    float sp00, sp01, sp11;                // spd_core (symmetric)
};

// One batch element: 2 v_rsq + ~25 FMA, no div/sqrt.
__device__ __forceinline__ void compute_one(
    float xe, float pe, float de, float fe, const Params& P,
    v2f& mv, v4f& cv)
{
    float om = 1.0f - pe;

    // Sigma_bar = Sigma2 + p*(Sigma1-Sigma2) + EPS*I
    float a  = fmaf(pe, P.da, P.s2a) + EPS;
    float b  = fmaf(pe, P.db, P.s2b);
    float cc = fmaf(pe, P.dc, P.s2c) + EPS;

    // Cholesky via rsqrt: L=[[l00,0],[t,l11]], U=L^T
    float inv_l00 = __builtin_amdgcn_rsqf(a);
    float t       = b * inv_l00;                 // l10
    float dd      = fmaf(-t, t, cc);             // Schur complement = l11^2
    float inv_l11 = __builtin_amdgcn_rsqf(dd);

    // mu_bar - r
    float mb0 = fmaf(pe, P.dmu0, P.mu20r);
    float mb1 = fmaf(pe, P.dmu1, P.mu21r);

    // adj = p*(1 - dlnf_dp*(1-p)); signal_i = mb_i * (phi_i0*adj + phi_i1)
    float adj  = pe * fmaf(-de, om, 1.0f);
    float sig0 = mb0 * fmaf(P.phi00, adj, P.phi01);
    float sig1 = mb1 * fmaf(P.phi10, adj, P.phi11);

    // back-substitution: U x = sig
    float sti1 = sig1 * inv_l11;
    float sti0 = fmaf(-t, sti1, sig0) * inv_l00;

    float nxo = P.omega - xe;
    mv.x = nxo * sti0;
    mv.y = nxo * sti1;

    // inv_U = [[1/l00, -t/(l00*l11)],[0, 1/l11]]
    float iu00 = inv_l00;
    float iu11 = inv_l11;
    float iu01 = -(t * inv_l00) * inv_l11;

    // C = inv_U @ spd @ inv_U^T
    float M00 = fmaf(iu00, P.sp00, iu01 * P.sp01);
    float M01 = fmaf(iu00, P.sp01, iu01 * P.sp11);
    float M10 = iu11 * P.sp01;
    float M11 = iu11 * P.sp11;
    float C00 = fmaf(M00, iu00, M01 * iu01);
    float C01 = M01 * iu11;
    float C10 = fmaf(M10, iu00, M11 * iu01);
    float C11 = M11 * iu11;

    float scale = P.half_lam * fe;               // 0.5*lambda*f
    float off   = 0.5f * scale * (C01 + C10);
    cv.x = fmaf(scale, C00, EPS);
    cv.y = off;
    cv.z = off;
    cv.w = fmaf(scale, C11, EPS);
}

__device__ __forceinline__ Params load_params(
    const float* omega_p, const float* mu1, const float* mu2,
    const float* S1, const float* S2, const float* phi, const float* ct,
    const int* lambda_p, const int* r_p)
{
    Params P;
    P.omega    = omega_p[0];
    float lam  = (float)lambda_p[0];
    P.half_lam = 0.5f * lam;
    float r    = (float)r_p[0];
    float mu10 = mu1[0], mu11 = mu1[1], mu20 = mu2[0], mu21 = mu2[1];
    P.mu20r = mu20 - r;    P.mu21r = mu21 - r;
    P.dmu0  = mu10 - mu20; P.dmu1  = mu11 - mu21;
    P.s2a = S2[0]; P.s2b = S2[2]; P.s2c = S2[3];
    P.da  = S1[0] - P.s2a; P.db = S1[2] - P.s2b; P.dc = S1[3] - P.s2c;
    P.phi00 = phi[0]; P.phi01 = phi[1]; P.phi10 = phi[2]; P.phi11 = phi[3];
    // spd_core from cov_tril_unconstrained: tril=[[e^ct00,0],[ct10,e^ct11]]
    float e0 = expf(ct[0]);
    float e1 = expf(ct[3]);
    float t10 = ct[2];
    P.sp00 = e0 * e0;
    P.sp01 = t10 * e0;
    P.sp11 = fmaf(t10, t10, e1 * e1);
    return P;
}

// 1 element per thread: EVERY memory instruction is fully lane-contiguous —
// loads 4B/lane (256B/instr), mean store 8B/lane (512B/instr), cov store
// 16B/lane (1KB/instr). Per-instruction coalescing is what the L2 write-
// combine path needs (4/8-elem-per-thread variants amplified WRITE_SIZE).
__global__ __launch_bounds__(256) void poemv_kernel(
    const float* __restrict__ x, const float* __restrict__ omega_p,
    const float* __restrict__ p, const float* __restrict__ dlnf_dp,
    const float* __restrict__ f,
    const float* __restrict__ mu1, const float* __restrict__ mu2,
    const float* __restrict__ S1, const float* __restrict__ S2,
    const float* __restrict__ phi, const float* __restrict__ ct,
    const int* __restrict__ lambda_p, const int* __restrict__ r_p,
    float* __restrict__ out_mean, float* __restrict__ out_cov, int B)
{
    int b = blockIdx.x * blockDim.x + threadIdx.x;
    if (b >= B) return;

    // issue the 4 data loads before the (scalar) param loads' consumers
    float xe = x[b];
    float pe = p[b];
    float de = dlnf_dp[b];
    float fe = f[b];

    Params P = load_params(omega_p, mu1, mu2, S1, S2, phi, ct, lambda_p, r_p);

    v2f mv; v4f cv;
    compute_one(xe, pe, de, fe, P, mv, cv);

    ((v2f*)out_mean)[b] = mv;
    ((v4f*)out_cov)[b]  = cv;
}

extern "C" void kernel_launch(void* const* d_in, const int* in_sizes, int n_in,
                              void* d_out, int out_size, void* d_ws, size_t ws_size,
                              hipStream_t stream) {
    const float* x     = (const float*)d_in[0];
    const float* omega = (const float*)d_in[1];
    const float* p     = (const float*)d_in[2];
    const float* dlnf  = (const float*)d_in[3];
    const float* f     = (const float*)d_in[4];
    const float* mu1   = (const float*)d_in[5];
    const float* mu2   = (const float*)d_in[6];
    const float* S1    = (const float*)d_in[7];
    const float* S2    = (const float*)d_in[8];
    const float* phi   = (const float*)d_in[9];
    const float* ct    = (const float*)d_in[10];
    const int*   lam   = (const int*)d_in[11];
    const int*   r     = (const int*)d_in[12];

    int B = in_sizes[0];
    float* out_mean = (float*)d_out;
    float* out_cov  = out_mean + (size_t)B * 2;

    int threads = 256;
    int blocks = (B + threads - 1) / threads;
    poemv_kernel<<<blocks, threads, 0, stream>>>(
        x, omega, p, dlnf, f, mu1, mu2, S1, S2, phi, ct, lam, r,
        out_mean, out_cov, B);
}